// Round 5
// baseline (307.981 us; speedup 1.0000x reference)
//
#include <hip/hip_runtime.h>

#define SEQ 2048
#define DM  1024
#define NH  16
#define HDIM 64

typedef __bf16   bf16x8 __attribute__((ext_vector_type(8)));
typedef float    f32x4  __attribute__((ext_vector_type(4)));
typedef _Float16 half8  __attribute__((ext_vector_type(8)));
typedef _Float16 half4v __attribute__((ext_vector_type(4)));

// async global->LDS 16B (linear LDS dst = wave-uniform base + lane*16)
__device__ __forceinline__ void gload16(const void* g, void* l) {
    __builtin_amdgcn_global_load_lds(
        (const __attribute__((address_space(1))) unsigned int*)g,
        (__attribute__((address_space(3))) unsigned int*)l, 16, 0, 0);
}

// ------------------------------------------------ sentinel: zero the output
__global__ void zero_out(float* __restrict__ out, int n) {
    int i = blockIdx.x * 256 + threadIdx.x;
    if (i < n) out[i] = 0.f;
}

// --------------------------- batched fp32->bf16: 6 weights + hs in 2 slices
struct CvtBatch { const float* src[8]; __bf16* dst[8]; };
__global__ __launch_bounds__(256) void cvt_all(CvtBatch cb) {
    const int z = blockIdx.y;
    int i = blockIdx.x * 256 + threadIdx.x;           // 512*256 = 131072 chunks
    const float4* s = reinterpret_cast<const float4*>(cb.src[z]) + (size_t)i * 2;
    float4 x = s[0], y = s[1];
    bf16x8 o;
    o[0] = (__bf16)x.x; o[1] = (__bf16)x.y; o[2] = (__bf16)x.z; o[3] = (__bf16)x.w;
    o[4] = (__bf16)y.x; o[5] = (__bf16)y.y; o[6] = (__bf16)y.z; o[7] = (__bf16)y.w;
    reinterpret_cast<bf16x8*>(cb.dst[z])[i] = o;
}

// ---------------------------------------- Wsup = blockdiag(mixW) @ Wv (bf16)
__global__ __launch_bounds__(256) void wsup_k(
    const float* __restrict__ mixw, const float* __restrict__ Wv,
    const float* __restrict__ bv, const float* __restrict__ mixb,
    __bf16* __restrict__ w6, float* __restrict__ bsup)
{
    const int ho = blockIdx.x, h = ho >> 6, tid = threadIdx.x;
    __shared__ float mrow[64];
    if (tid < 64) mrow[tid] = mixw[(size_t)ho * 64 + tid];
    __syncthreads();
    const int c0 = tid * 4;
    float a0 = 0.f, a1 = 0.f, a2 = 0.f, a3 = 0.f;
    for (int dd = 0; dd < 64; ++dd) {
        const float4 wv4 = *reinterpret_cast<const float4*>(
            Wv + (size_t)(h * 64 + dd) * DM + c0);
        const float w = mrow[dd];
        a0 += w * wv4.x; a1 += w * wv4.y; a2 += w * wv4.z; a3 += w * wv4.w;
    }
    __bf16* dst = w6 + (size_t)ho * DM + c0;
    dst[0] = (__bf16)a0; dst[1] = (__bf16)a1; dst[2] = (__bf16)a2; dst[3] = (__bf16)a3;
    if (tid == 0) {
        float b = mixb[ho];
        for (int dd = 0; dd < 64; ++dd) b += mrow[dd] * bv[h * 64 + dd];
        bsup[ho] = b;
    }
}

// ---------------------------------------------------------------- MFMA GEMM
// C[m][n] = sum_k A[m][k] * W[n][k] + bias[n]   (B^T layout: both K-contig)
// Staging via global_load_lds(16B): linear LDS dst, XOR-swizzle applied to
// the GLOBAL source chunk index (involution; read-side XOR recovers).
// mode 2: f32 + resid add; mode 3: f16 store.
struct GemmBatch {
    const __bf16* A;
    const __bf16* W[6];
    const float*  bias[6];
    void*         out[6];
    int           mode[6];
    const float*  resid;
};

__device__ __forceinline__ int swz4(int r) { return (r ^ (r >> 2)) & 3; }

__global__ __launch_bounds__(256) void gemm_bt(GemmBatch g) {
    const int z = blockIdx.z;
    const __bf16* __restrict__ A = g.A;
    const __bf16* __restrict__ W = g.W[z];
    const int ncol0 = blockIdx.x * 128;
    const int mrow0 = blockIdx.y * 128;
    const int tid = threadIdx.x, lane = tid & 63, wv = tid >> 6;
    const int wm = wv >> 1, wn = wv & 1;
    const int fr = lane & 15, fj = lane >> 4;

    __shared__ __bf16 As[128 * 32];
    __shared__ __bf16 Bs[128 * 32];

    f32x4 acc[4][4];
#pragma unroll
    for (int i = 0; i < 4; ++i)
#pragma unroll
        for (int j = 0; j < 4; ++j)
#pragma unroll
            for (int e = 0; e < 4; ++e) acc[i][j][e] = 0.f;

    const int row0 = wv * 16 + (lane >> 2);
    const int row1 = row0 + 64;
    const int jl   = lane & 3;
    const int dstA0 = row0 * 32 + jl * 8;
    const int dstA1 = row1 * 32 + jl * 8;
    const __bf16* ApS0 = A + (size_t)(mrow0 + row0) * DM + (jl ^ swz4(row0)) * 8;
    const __bf16* ApS1 = A + (size_t)(mrow0 + row1) * DM + (jl ^ swz4(row1)) * 8;
    const __bf16* WpS0 = W + (size_t)(ncol0 + row0) * DM + (jl ^ swz4(row0)) * 8;
    const __bf16* WpS1 = W + (size_t)(ncol0 + row1) * DM + (jl ^ swz4(row1)) * 8;

    for (int kt = 0; kt < DM; kt += 32) {
        __syncthreads();
        gload16(ApS0 + kt, As + dstA0);
        gload16(ApS1 + kt, As + dstA1);
        gload16(WpS0 + kt, Bs + dstA0);
        gload16(WpS1 + kt, Bs + dstA1);
        __syncthreads();

        bf16x8 af[4], bfv[4];
#pragma unroll
        for (int mf = 0; mf < 4; ++mf) {
            int r = wm * 64 + mf * 16 + fr;
            af[mf] = *(const bf16x8*)(As + r * 32 + ((fj ^ swz4(r)) << 3));
        }
#pragma unroll
        for (int nf = 0; nf < 4; ++nf) {
            int r = wn * 64 + nf * 16 + fr;
            bfv[nf] = *(const bf16x8*)(Bs + r * 32 + ((fj ^ swz4(r)) << 3));
        }
#pragma unroll
        for (int mf = 0; mf < 4; ++mf)
#pragma unroll
            for (int nf = 0; nf < 4; ++nf)
                acc[mf][nf] = __builtin_amdgcn_mfma_f32_16x16x32_bf16(
                    af[mf], bfv[nf], acc[mf][nf], 0, 0, 0);
    }

    const int mode = g.mode[z];
    const float* __restrict__ bias = g.bias[z];
#pragma unroll
    for (int mf = 0; mf < 4; ++mf) {
#pragma unroll
        for (int nf = 0; nf < 4; ++nf) {
            const int col = ncol0 + wn * 64 + nf * 16 + fr;
            const int rw0 = mrow0 + wm * 64 + mf * 16 + fj * 4;
            const float bc = bias[col];
#pragma unroll
            for (int jj = 0; jj < 4; ++jj) {
                float vv = acc[mf][nf][jj] + bc;
                const size_t idx = (size_t)(rw0 + jj) * DM + col;
                if (mode == 3) {
                    ((_Float16*)g.out[z])[idx] = (_Float16)vv;
                } else {
                    if (mode == 2) vv += g.resid[idx];
                    ((float*)g.out[z])[idx] = vv;
                }
            }
        }
    }
}

// ------------------------------------- amplitudes / phases, 16 lanes/head
__global__ __launch_bounds__(256) void amp_fast(
    const float* __restrict__ hs,
    const float* __restrict__ amp_w, const float* __restrict__ amp_b,
    const float* __restrict__ ph_w,  const float* __restrict__ ph_b,
    float* __restrict__ cA, float* __restrict__ sA)
{
    const int s = blockIdx.x;
    __shared__ float hrow[DM];
    for (int i = threadIdx.x; i < DM; i += 256)
        hrow[i] = hs[(size_t)s * DM + i];
    __syncthreads();
    const int h = threadIdx.x >> 4, sub = threadIdx.x & 15;
    const float* aw = amp_w + (size_t)h * DM;
    const float* pw = ph_w  + (size_t)h * DM;
    float da = 0.f, dp = 0.f;
    for (int k = sub; k < DM; k += 16) {
        const float hv = hrow[k];
        da += hv * aw[k];
        dp += hv * pw[k];
    }
#pragma unroll
    for (int off = 8; off >= 1; off >>= 1) {
        da += __shfl_xor(da, off);
        dp += __shfl_xor(dp, off);
    }
    if (sub == 0) {
        da += amp_b[h]; dp += ph_b[h];
        float amp = 1.f / (1.f + expf(-da));
        float ph  = tanhf(dp) * 3.14159265358979323846f;
        cA[s * NH + h] = 0.3f * amp * cosf(ph);
        sA[s * NH + h] = 0.3f * amp * sinf(ph);
    }
}

// ----------------- mixedT[h*64+o][s] = v + cA*sup + sA*roll(sup)  (f16)
__global__ __launch_bounds__(256) void mixT_fuse(
    const _Float16* __restrict__ vb, const _Float16* __restrict__ supf,
    const float* __restrict__ cA, const float* __restrict__ sA,
    _Float16* __restrict__ mixedT)
{
    const int h = blockIdx.x, st = blockIdx.y;        // 16 x 64
    const int o = threadIdx.x >> 2, sc = threadIdx.x & 3;
    const int s0 = st * 32 + sc * 8;
    const int ho = h * 64 + o, op = h * 64 + ((o + 63) & 63);
    half8 m;
#pragma unroll
    for (int e = 0; e < 8; ++e) {
        const int s = s0 + e;
        const float v  = (float)vb[(size_t)s * DM + ho];
        const float su = (float)supf[(size_t)s * DM + ho];
        const float s2 = (float)supf[(size_t)s * DM + op];
        m[e] = (_Float16)(v + cA[s * NH + h] * su + sA[s * NH + h] * s2);
    }
    *reinterpret_cast<half8*>(mixedT + (size_t)ho * SEQ + s0) = m;
}

// ---------------------------------------------------- flash MFMA attention
// KV-SPLIT-2: blockIdx.z in {0,1} owns keys [z*1024, z*1024+1024).
// Block: 64 q-rows x 1 head, 4 waves x 16 q-rows. KV tiles of 64 keys.
// Defer-max online softmax (m0=0, THR=8). Band sparsity on the entanglement
// term (skip beyond |delta|=160; contribution < 2e-10).
// Writes UNNORMALIZED O (f16) + per-row (m,l); merge_attn combines splits.
__global__ __launch_bounds__(256) void attn_mfma(
    const _Float16* __restrict__ q, const _Float16* __restrict__ k,
    const _Float16* __restrict__ eq, const _Float16* __restrict__ ek,
    const _Float16* __restrict__ mixedT,
    _Float16* __restrict__ U, float* __restrict__ ml)
{
    const int h = blockIdx.y;
    const int q0 = blockIdx.x * 64;
    const int sp = blockIdx.z;
    const int kb0 = sp * (SEQ / 2);
    const int tid = threadIdx.x, lane = tid & 63, wv = tid >> 6;
    const int lo = lane & 15, hi = lane >> 4;
    const int hoff = h * HDIM;

    __shared__ _Float16 Kt[64 * 64];
    __shared__ _Float16 Et[64 * 64];
    __shared__ _Float16 Mt[64 * 64];
    __shared__ _Float16 Pt[4][64 * 18];    // per-wave [64key][16row+2pad]

    half8 qa[2], ea[2];
#pragma unroll
    for (int kk = 0; kk < 2; ++kk) {
        const int row = q0 + wv * 16 + lo;
        qa[kk] = *(const half8*)(q  + (size_t)row * DM + hoff + kk * 32 + hi * 8);
        ea[kk] = *(const half8*)(eq + (size_t)row * DM + hoff + kk * 32 + hi * 8);
    }

    f32x4 oacc[4];
    float mr[4], lr[4];
#pragma unroll
    for (int j = 0; j < 4; ++j) { mr[j] = 0.f; lr[j] = 0.f; }
#pragma unroll
    for (int n = 0; n < 4; ++n)
#pragma unroll
        for (int e = 0; e < 4; ++e) oacc[n][e] = 0.f;

    const int srow = tid >> 3, schk = tid & 7;
    const int sdst0 = srow * 64 + ((schk ^ (srow & 7)) << 3);
    const int sdst1 = (srow + 32) * 64 + ((schk ^ (srow & 7)) << 3);

    #define IN_BAND(kt_) ({ int _a = (kt_) - (q0 + 63); int _b = q0 - ((kt_) + 63); \
                            int _d = _a > 0 ? _a : (_b > 0 ? _b : 0); _d <= 160; })

    bool diagCur = IN_BAND(kb0);
    half8 rk0 = *(const half8*)(k  + (size_t)(kb0 + srow) * DM + hoff + schk * 8);
    half8 rk1 = *(const half8*)(k  + (size_t)(kb0 + srow + 32) * DM + hoff + schk * 8);
    half8 rm0 = *(const half8*)(mixedT + (size_t)(hoff + srow) * SEQ + kb0 + schk * 8);
    half8 rm1 = *(const half8*)(mixedT + (size_t)(hoff + srow + 32) * SEQ + kb0 + schk * 8);
    half8 re0, re1;
    if (diagCur) {
        re0 = *(const half8*)(ek + (size_t)(kb0 + srow) * DM + hoff + schk * 8);
        re1 = *(const half8*)(ek + (size_t)(kb0 + srow + 32) * DM + hoff + schk * 8);
    }

    const int kend = kb0 + SEQ / 2;
    for (int kt = kb0; kt < kend; kt += 64) {
        __syncthreads();
        *(half8*)&Kt[sdst0] = rk0; *(half8*)&Kt[sdst1] = rk1;
        *(half8*)&Mt[sdst0] = rm0; *(half8*)&Mt[sdst1] = rm1;
        if (diagCur) { *(half8*)&Et[sdst0] = re0; *(half8*)&Et[sdst1] = re1; }
        __syncthreads();
        const bool diagNext = (kt + 64 < kend) && IN_BAND(kt + 64);
        if (kt + 64 < kend) {
            const int nt = kt + 64;
            rk0 = *(const half8*)(k  + (size_t)(nt + srow) * DM + hoff + schk * 8);
            rk1 = *(const half8*)(k  + (size_t)(nt + srow + 32) * DM + hoff + schk * 8);
            rm0 = *(const half8*)(mixedT + (size_t)(hoff + srow) * SEQ + nt + schk * 8);
            rm1 = *(const half8*)(mixedT + (size_t)(hoff + srow + 32) * SEQ + nt + schk * 8);
            if (diagNext) {
                re0 = *(const half8*)(ek + (size_t)(nt + srow) * DM + hoff + schk * 8);
                re1 = *(const half8*)(ek + (size_t)(nt + srow + 32) * DM + hoff + schk * 8);
            }
        }

        // ---- QK^T (always) and EQ*EK^T (band tiles only)
        f32x4 sa[4], se[4];
#pragma unroll
        for (int n = 0; n < 4; ++n)
#pragma unroll
            for (int e = 0; e < 4; ++e) { sa[n][e] = 0.f; se[n][e] = 0.f; }
#pragma unroll
        for (int kk = 0; kk < 2; ++kk)
#pragma unroll
            for (int nf = 0; nf < 4; ++nf) {
                const int rrow = lo + 16 * nf;
                const int coff = rrow * 64 + (((hi + 4 * kk) ^ (rrow & 7)) << 3);
                half8 kb = *(const half8*)&Kt[coff];
                sa[nf] = __builtin_amdgcn_mfma_f32_16x16x32_f16(qa[kk], kb, sa[nf], 0, 0, 0);
            }
        if (diagCur) {
#pragma unroll
            for (int kk = 0; kk < 2; ++kk)
#pragma unroll
                for (int nf = 0; nf < 4; ++nf) {
                    const int rrow = lo + 16 * nf;
                    const int coff = rrow * 64 + (((hi + 4 * kk) ^ (rrow & 7)) << 3);
                    half8 eb = *(const half8*)&Et[coff];
                    se[nf] = __builtin_amdgcn_mfma_f32_16x16x32_f16(ea[kk], eb, se[nf], 0, 0, 0);
                }
        }

        // ---- logits + defer-max check
        float lg[4][4];
        bool exc = false;
        const int qrow = q0 + wv * 16 + hi * 4;
        if (diagCur) {
#pragma unroll
            for (int nf = 0; nf < 4; ++nf) {
                const int key = kt + nf * 16 + lo;
#pragma unroll
                for (int j = 0; j < 4; ++j) {
                    int dd = qrow + j - key; dd = dd < 0 ? -dd : dd;
                    const float dec = exp2f(-0.14426950408889634f * (float)dd);
                    const float v = 0.125f * sa[nf][j] + 0.0625f * se[nf][j] * dec;
                    lg[nf][j] = v;
                    exc |= (v > mr[j] + 8.f);
                }
            }
        } else {
#pragma unroll
            for (int nf = 0; nf < 4; ++nf)
#pragma unroll
                for (int j = 0; j < 4; ++j) {
                    const float v = 0.125f * sa[nf][j];
                    lg[nf][j] = v;
                    exc |= (v > mr[j] + 8.f);
                }
        }
        if (__any((int)exc)) {                       // rare rescale path
#pragma unroll
            for (int j = 0; j < 4; ++j) {
                float tm = fmaxf(fmaxf(lg[0][j], lg[1][j]), fmaxf(lg[2][j], lg[3][j]));
#pragma unroll
                for (int off = 8; off >= 1; off >>= 1) tm = fmaxf(tm, __shfl_xor(tm, off));
                const float mnew = fmaxf(mr[j], tm);
                const float corr = __expf(mr[j] - mnew);
                lr[j] *= corr; mr[j] = mnew;
#pragma unroll
                for (int nfd = 0; nfd < 4; ++nfd) oacc[nfd][j] *= corr;
            }
        }
        // ---- P = exp(lg - m), lane-local l accumulation, P -> LDS (f16)
        _Float16* Pw = Pt[wv];
#pragma unroll
        for (int nf = 0; nf < 4; ++nf) {
            half4v pv;
#pragma unroll
            for (int j = 0; j < 4; ++j) {
                const float p = __expf(lg[nf][j] - mr[j]);
                lr[j] += p;
                pv[j] = (_Float16)p;
            }
            *(half4v*)&Pw[(lo + 16 * nf) * 18 + hi * 4] = pv;
        }
        __asm__ volatile("s_waitcnt lgkmcnt(0)" ::: "memory");

        // ---- PV: oacc += P * mixed
#pragma unroll
        for (int kk = 0; kk < 2; ++kk) {
            half8 mb[4];
#pragma unroll
            for (int nfd = 0; nfd < 4; ++nfd) {
                const int rrow = lo + 16 * nfd;
                mb[nfd] = *(const half8*)&Mt[rrow * 64 + (((hi + 4 * kk) ^ (rrow & 7)) << 3)];
            }
            half8 pa;
#pragma unroll
            for (int e = 0; e < 8; ++e)
                pa[e] = Pw[(kk * 32 + hi * 8 + e) * 18 + lo];
#pragma unroll
            for (int nfd = 0; nfd < 4; ++nfd)
                oacc[nfd] = __builtin_amdgcn_mfma_f32_16x16x32_f16(pa, mb[nfd], oacc[nfd], 0, 0, 0);
        }
        diagCur = diagNext;
    }
    #undef IN_BAND

    // ---- epilogue: reduce l over 16-lane row group; store U (unnorm) + m,l
#pragma unroll
    for (int j = 0; j < 4; ++j) {
#pragma unroll
        for (int off = 8; off >= 1; off >>= 1) lr[j] += __shfl_xor(lr[j], off);
    }
    const int qrow = q0 + wv * 16 + hi * 4;
    _Float16* Us = U + (size_t)sp * SEQ * DM;
#pragma unroll
    for (int nfd = 0; nfd < 4; ++nfd) {
        const int d = hoff + lo + 16 * nfd;
#pragma unroll
        for (int j = 0; j < 4; ++j)
            Us[(size_t)(qrow + j) * DM + d] = (_Float16)oacc[nfd][j];
    }
    if (lo == 0) {
#pragma unroll
        for (int j = 0; j < 4; ++j) {
            const size_t mi = ((size_t)(sp * SEQ + qrow + j) * NH + h) * 2;
            ml[mi] = mr[j]; ml[mi + 1] = lr[j];
        }
    }
}

// ----------------------------------- merge 2 KV-splits -> ctx (bf16)
__global__ __launch_bounds__(256) void merge_attn(
    const _Float16* __restrict__ U, const float* __restrict__ ml,
    __bf16* __restrict__ ctx)
{
    const int idx = blockIdx.x * 256 + threadIdx.x;   // 262144 total
    const int chunk = idx & 7, h = (idx >> 3) & 15, s = idx >> 7;
    const size_t mi0 = ((size_t)s * NH + h) * 2;
    const size_t mi1 = ((size_t)(SEQ + s) * NH + h) * 2;
    const float m0 = ml[mi0], l0 = ml[mi0 + 1];
    const float m1 = ml[mi1], l1 = ml[mi1 + 1];
    const float M = fmaxf(m0, m1);
    const float a0 = __expf(m0 - M), a1 = __expf(m1 - M);
    const float Linv = 1.f / (l0 * a0 + l1 * a1);
    const float w0 = a0 * Linv, w1 = a1 * Linv;
    const size_t off = (size_t)s * DM + h * 64 + chunk * 8;
    const half8 u0 = *(const half8*)(U + off);
    const half8 u1 = *(const half8*)(U + (size_t)SEQ * DM + off);
    __bf16* dst = ctx + off;
#pragma unroll
    for (int e = 0; e < 8; ++e)
        dst[e] = (__bf16)((float)u0[e] * w0 + (float)u1[e] * w1);
}

// --------------------------------------------- layer norm, FP32 OUTPUT
__global__ __launch_bounds__(256) void lnorm_f32(
    const float* __restrict__ res, const float* __restrict__ g,
    const float* __restrict__ b, float* __restrict__ out)
{
    const int row = blockIdx.x, tid = threadIdx.x;
    const int wave = tid >> 6, lane = tid & 63;
    __shared__ float red[8];
    const float4 x = reinterpret_cast<const float4*>(res + (size_t)row * DM)[tid];
    float s  = x.x + x.y + x.z + x.w;
    float s2 = x.x * x.x + x.y * x.y + x.z * x.z + x.w * x.w;
#pragma unroll
    for (int off = 32; off >= 1; off >>= 1) {
        s  += __shfl_xor(s, off);
        s2 += __shfl_xor(s2, off);
    }
    if (lane == 0) { red[wave] = s; red[4 + wave] = s2; }
    __syncthreads();
    s  = red[0] + red[1] + red[2] + red[3];
    s2 = red[4] + red[5] + red[6] + red[7];
    const float mu  = s * (1.f / DM);
    const float var = s2 * (1.f / DM) - mu * mu;
    const float inv = rsqrtf(var + 1e-5f);
    const int col = tid * 4;
    float4 o;
    o.x = (x.x - mu) * inv * g[col + 0] + b[col + 0];
    o.y = (x.y - mu) * inv * g[col + 1] + b[col + 1];
    o.z = (x.z - mu) * inv * g[col + 2] + b[col + 2];
    o.w = (x.w - mu) * inv * g[col + 3] + b[col + 3];
    reinterpret_cast<float4*>(out + (size_t)row * DM)[tid] = o;
}

// ---------------------------------------------------------------- launch
// OUTPUT IS FP32. ws layout (~34.3 MB):
//   [0,4M)    hsb bf16        -> overlaid by mixedT f16 (hsb dead after g1)
//   [4,16M)   w0..w5 bf16 (Wq,Wk,Wv,Weq,Wek,Wo), 2MB each
//             -> w0..w3 overlaid by U f16 (8MB, 2 splits) after g1;
//                w4 overlaid by ml (512KB) after g1; w5 stays (g3)
//   [16,18M)  w6 = Wsup bf16
//   [18,22M)  qf f16   [22,26M) kf f16   } res f32 overlays [18,26M) post-attn
//   [26,30M)  eqf f16  [30,34M) ekf f16
//   [34M..)   cA (128K), sA (128K), bsup (4K)
// d_out staging: vb f16 [0,4M), supf f16 [4,8M); dead after mixT_fuse;
// ctx bf16 (from merge_attn) occupies [0,4M); lnorm rewrites full 8MB fp32.
extern "C" void kernel_launch(void* const* d_in, const int* in_sizes, int n_in,
                              void* d_out, int out_size, void* d_ws, size_t ws_size,
                              hipStream_t stream) {
    const float* hs   = (const float*)d_in[0];
    const float* Wq   = (const float*)d_in[1];
    const float* bq   = (const float*)d_in[2];
    const float* Wk   = (const float*)d_in[3];
    const float* bk   = (const float*)d_in[4];
    const float* Wv   = (const float*)d_in[5];
    const float* bv   = (const float*)d_in[6];
    const float* Wo   = (const float*)d_in[7];
    const float* bo   = (const float*)d_in[8];
    const float* Weq  = (const float*)d_in[9];
    const float* beq  = (const float*)d_in[10];
    const float* Wek  = (const float*)d_in[11];
    const float* bek  = (const float*)d_in[12];
    const float* ampw = (const float*)d_in[13];
    const float* ampb = (const float*)d_in[14];
    const float* phw  = (const float*)d_in[15];
    const float* phb  = (const float*)d_in[16];
    const float* mixw = (const float*)d_in[17];
    const float* mixb = (const float*)d_in[18];
    const float* lng  = (const float*)d_in[19];
    const float* lnb  = (const float*)d_in[20];
    float* out = (float*)d_out;

    static const int expect[21] = {
        2097152, 1048576, 1024, 1048576, 1024, 1048576, 1024, 1048576, 1024,
        1048576, 1024, 1048576, 1024, 16384, 16, 16384, 16, 65536, 1024,
        1024, 1024};
    bool ok = (n_in == 21) && (out_size == 2097152);
    if (ok) for (int i = 0; i < 21; ++i) ok = ok && (in_sizes[i] == expect[i]);
    if (!ok) {
        zero_out<<<(out_size + 255) / 256, 256, 0, stream>>>(out, out_size);
        return;
    }

    char* ws = (char*)d_ws;
    __bf16*   hsb = (__bf16*)ws;
    __bf16*   w0  = (__bf16*)(ws + (4  << 20));
    __bf16*   w1  = (__bf16*)(ws + (6  << 20));
    __bf16*   w2  = (__bf16*)(ws + (8  << 20));
    __bf16*   w3  = (__bf16*)(ws + (10 << 20));
    __bf16*   w4  = (__bf16*)(ws + (12 << 20));
    __bf16*   w5  = (__bf16*)(ws + (14 << 20));
    __bf16*   w6  = (__bf16*)(ws + (16 << 20));
    _Float16* qf  = (_Float16*)(ws + (18 << 20));
    _Float16* kf  = (_Float16*)(ws + (22 << 20));
    _Float16* eqf = (_Float16*)(ws + (26 << 20));
    _Float16* ekf = (_Float16*)(ws + (30 << 20));
    float*    cA  = (float*)(ws + (34 << 20));
    float*    sA  = cA + SEQ * NH;
    float*    bsup = sA + SEQ * NH;
    _Float16* mxT = (_Float16*)hsb;            // overlay: hsb dead after g1
    _Float16* U   = (_Float16*)(ws + (4 << 20));  // overlay w0..w3 (dead after g1)
    float*    ml  = (float*)(ws + (12 << 20));    // overlay w4 (dead after g1)
    float*    res = (float*)(ws + (18 << 20));    // overlay qf/kf (dead after attn)
    _Float16* vb   = (_Float16*)d_out;
    _Float16* supf = (_Float16*)((char*)d_out + (4 << 20));
    __bf16*   ctx  = (__bf16*)d_out;

    CvtBatch cb;
    cb.src[0] = Wq;  cb.dst[0] = w0;
    cb.src[1] = Wk;  cb.dst[1] = w1;
    cb.src[2] = Wv;  cb.dst[2] = w2;
    cb.src[3] = Weq; cb.dst[3] = w3;
    cb.src[4] = Wek; cb.dst[4] = w4;
    cb.src[5] = Wo;  cb.dst[5] = w5;
    cb.src[6] = hs;                cb.dst[6] = hsb;
    cb.src[7] = hs + SEQ * DM / 2; cb.dst[7] = hsb + SEQ * DM / 2;
    cvt_all<<<dim3(512, 8), 256, 0, stream>>>(cb);

    wsup_k<<<1024, 256, 0, stream>>>(mixw, Wv, bv, mixb, w6, bsup);
    amp_fast<<<SEQ, 256, 0, stream>>>(hs, ampw, ampb, phw, phb, cA, sA);

    GemmBatch g1 = {};
    g1.A = hsb;
    g1.W[0] = w0; g1.bias[0] = bq;   g1.out[0] = qf;   g1.mode[0] = 3;
    g1.W[1] = w1; g1.bias[1] = bk;   g1.out[1] = kf;   g1.mode[1] = 3;
    g1.W[2] = w2; g1.bias[2] = bv;   g1.out[2] = vb;   g1.mode[2] = 3;
    g1.W[3] = w3; g1.bias[3] = beq;  g1.out[3] = eqf;  g1.mode[3] = 3;
    g1.W[4] = w4; g1.bias[4] = bek;  g1.out[4] = ekf;  g1.mode[4] = 3;
    g1.W[5] = w6; g1.bias[5] = bsup; g1.out[5] = supf; g1.mode[5] = 3;
    g1.resid = nullptr;
    gemm_bt<<<dim3(DM / 128, SEQ / 128, 6), 256, 0, stream>>>(g1);

    mixT_fuse<<<dim3(NH, SEQ / 32), 256, 0, stream>>>(vb, supf, cA, sA, mxT);

    attn_mfma<<<dim3(SEQ / 64, NH, 2), 256, 0, stream>>>(
        qf, kf, eqf, ekf, mxT, U, ml);
    merge_attn<<<SEQ * NH * 8 / 256, 256, 0, stream>>>(U, ml, ctx);

    GemmBatch g3 = {};
    g3.A = ctx;
    g3.W[0] = w5; g3.bias[0] = bo; g3.out[0] = res; g3.mode[0] = 2;
    g3.resid = hs;
    gemm_bt<<<dim3(DM / 128, SEQ / 128, 1), 256, 0, stream>>>(g3);

    lnorm_f32<<<SEQ, 256, 0, stream>>>(res, lng, lnb, out);
}